// Round 1
// baseline (162.414 us; speedup 1.0000x reference)
//
#include <hip/hip_runtime.h>
#include <math.h>

#define N_NODES 8192
#define E_EDGES 262144
#define DIM 256
#define NEG_SLOPE 0.2f

// ---------------- workspace layout (bytes) ----------------
#define OFF_H        0u                     // 8192*256 f32 = 8 MB
#define OFF_BITMAP   8388608u               // 8192*8192 bits = 8 MB (uint32[2097152])
#define OFF_CNT      16777216u              // 8192 int
#define OFF_CURSOR   16809984u              // 8192 int
#define OFF_SALL     16842752u              // 256 f32 (1 KB)
#define ZERO_BASE    OFF_BITMAP
#define ZERO_BYTES   (8388608u + 32768u + 32768u + 1024u)   // bitmap+cnt+cursor+S_all
#define OFF_S        16843776u              // 8192 f32
#define OFF_T        16876544u              // 8192 f32
#define OFF_ROWSTART 16909312u              // 8193 int
#define OFF_FLAGS    16942336u              // E bytes
#define OFF_CSR      17204480u              // E int
// total ~17.4 MB

// ---------------- GEMM: h = x @ W  (8192x256 * 256x256, fp32) ----------------
// block 256 threads, tile 64(m) x 64(n), K-step 16, 4x4 micro-tile per thread
__global__ __launch_bounds__(256) void gemm_kernel(const float* __restrict__ x,
                                                   const float* __restrict__ W,
                                                   float* __restrict__ h) {
  __shared__ float xT[16][64];   // [k][m]
  __shared__ float Ws[16][64];   // [k][n]
  const int bm = blockIdx.x * 64;
  const int bn = blockIdx.y * 64;
  const int t = threadIdx.x;
  const int tm = t & 15;
  const int tn = t >> 4;
  float acc[4][4] = {};
  for (int k0 = 0; k0 < DIM; k0 += 16) {
    {
      const int r = t & 63;
      const int kk = (t >> 6) << 2;
      const float4 xv = *(const float4*)(x + (size_t)(bm + r) * DIM + k0 + kk);
      xT[kk + 0][r] = xv.x;
      xT[kk + 1][r] = xv.y;
      xT[kk + 2][r] = xv.z;
      xT[kk + 3][r] = xv.w;
      const int kw = t >> 4;
      const int nw = (t & 15) << 2;
      *(float4*)(&Ws[kw][nw]) = *(const float4*)(W + (size_t)(k0 + kw) * DIM + bn + nw);
    }
    __syncthreads();
#pragma unroll
    for (int k = 0; k < 16; ++k) {
      const float4 av = *(const float4*)(&xT[k][tm << 2]);
      const float4 bv = *(const float4*)(&Ws[k][tn << 2]);
      const float a_[4] = {av.x, av.y, av.z, av.w};
      const float b_[4] = {bv.x, bv.y, bv.z, bv.w};
#pragma unroll
      for (int i = 0; i < 4; ++i)
#pragma unroll
        for (int j = 0; j < 4; ++j) acc[i][j] += a_[i] * b_[j];
    }
    __syncthreads();
  }
#pragma unroll
  for (int i = 0; i < 4; ++i) {
    const int m = bm + (tm << 2) + i;
    float4 o;
    o.x = acc[i][0]; o.y = acc[i][1]; o.z = acc[i][2]; o.w = acc[i][3];
    *(float4*)(h + (size_t)m * DIM + bn + (tn << 2)) = o;
  }
}

// ---------------- s[i] = h[i].a_src ; t[i] = h[i].a_tgt ----------------
// 1 wave per row, 4 waves per block
__global__ __launch_bounds__(256) void st_kernel(const float* __restrict__ h,
                                                 const float* __restrict__ a,
                                                 float* __restrict__ sv,
                                                 float* __restrict__ tv) {
  const int row = blockIdx.x * 4 + (threadIdx.x >> 6);
  const int lane = threadIdx.x & 63;
  const float4 hv = *(const float4*)(h + (size_t)row * DIM + (lane << 2));
  const float4 as = *(const float4*)(a + (lane << 2));
  const float4 at = *(const float4*)(a + DIM + (lane << 2));
  float ss = hv.x * as.x + hv.y * as.y + hv.z * as.z + hv.w * as.w;
  float tt = hv.x * at.x + hv.y * at.y + hv.z * at.z + hv.w * at.w;
#pragma unroll
  for (int off = 32; off > 0; off >>= 1) {
    ss += __shfl_down(ss, off);
    tt += __shfl_down(tt, off);
  }
  if (lane == 0) {
    sv[row] = ss;
    tv[row] = tt;
  }
}

// ---------------- S_all[c] = sum_m h[m][c] ----------------
__global__ __launch_bounds__(256) void colsum_kernel(const float* __restrict__ h,
                                                     float* __restrict__ S_all) {
  const int c = threadIdx.x;
  const int b = blockIdx.x;
  float sum = 0.f;
  const int m0 = b * 128;
  for (int m = m0; m < m0 + 128; ++m) sum += h[(size_t)m * DIM + c];
  atomicAdd(&S_all[c], sum);
}

// ---------------- edge dedup + per-row count ----------------
__global__ __launch_bounds__(256) void flag_count_kernel(const int* __restrict__ ei,
                                                         unsigned int* __restrict__ bitmap,
                                                         int* __restrict__ cnt,
                                                         unsigned char* __restrict__ flags) {
  const int k = blockIdx.x * 256 + threadIdx.x;
  const int src = ei[k];
  const int tgt = ei[E_EDGES + k];
  const unsigned int bit = (unsigned int)src * (unsigned int)N_NODES + (unsigned int)tgt;
  const unsigned int mask = 1u << (bit & 31u);
  const unsigned int old = atomicOr(&bitmap[bit >> 5], mask);
  const int isnew = (old & mask) ? 0 : 1;
  flags[k] = (unsigned char)isnew;
  if (isnew) atomicAdd(&cnt[src], 1);
}

// ---------------- exclusive prefix scan over cnt[8192] -> rowstart[8193] ----------------
__global__ __launch_bounds__(256) void scan_kernel(const int* __restrict__ cnt,
                                                   int* __restrict__ rowstart) {
  __shared__ int part[256];
  __shared__ int pref[257];
  const int t = threadIdx.x;
  const int base = t * 32;
  int sum = 0;
  for (int i = 0; i < 32; ++i) sum += cnt[base + i];
  part[t] = sum;
  __syncthreads();
  if (t == 0) {
    pref[0] = 0;
    for (int i = 0; i < 256; ++i) pref[i + 1] = pref[i] + part[i];
  }
  __syncthreads();
  int run = pref[t];
  for (int i = 0; i < 32; ++i) {
    rowstart[base + i] = run;
    run += cnt[base + i];
  }
  if (t == 255) rowstart[N_NODES] = run;
}

// ---------------- scatter accepted edges into CSR ----------------
__global__ __launch_bounds__(256) void scatter_kernel(const int* __restrict__ ei,
                                                      const unsigned char* __restrict__ flags,
                                                      const int* __restrict__ rowstart,
                                                      int* __restrict__ cursor,
                                                      int* __restrict__ csr) {
  const int k = blockIdx.x * 256 + threadIdx.x;
  if (!flags[k]) return;
  const int src = ei[k];
  const int tgt = ei[E_EDGES + k];
  const int pos = atomicAdd(&cursor[src], 1);
  csr[rowstart[src] + pos] = tgt;
}

// ---------------- per-row accumulate + finalize ----------------
// 1 wave per row; lane l owns output dims [4l, 4l+4)
__global__ __launch_bounds__(256) void row_kernel(const float* __restrict__ h,
                                                  const float* __restrict__ sv,
                                                  const float* __restrict__ tv,
                                                  const float* __restrict__ S_all,
                                                  const int* __restrict__ rowstart,
                                                  const int* __restrict__ csr,
                                                  float* __restrict__ out) {
  const int row = blockIdx.x * 4 + (threadIdx.x >> 6);
  const int lane = threadIdx.x & 63;
  const int beg = rowstart[row];
  const int end = rowstart[row + 1];
  const float srow = sv[row];

  float4 acc = {0.f, 0.f, 0.f, 0.f};
  float Z = 0.f;

  for (int e0 = beg; e0 < end; e0 += 64) {
    const int n = min(64, end - e0);
    float w = 0.f;
    int tg = 0;
    if (lane < n) {
      tg = csr[e0 + lane];
      float ev = srow + tv[tg];
      ev = (ev > 0.f) ? ev : NEG_SLOPE * ev;
      w = expm1f(ev);   // exp(e) - 1
    }
    for (int j = 0; j < n; ++j) {
      const float wj = __shfl(w, j);
      const int tj = __shfl(tg, j);
      const float4 hv = *(const float4*)(h + (size_t)tj * DIM + (lane << 2));
      acc.x += wj * hv.x;
      acc.y += wj * hv.y;
      acc.z += wj * hv.z;
      acc.w += wj * hv.w;
      Z += wj;
    }
  }

  const float4 sa = *(const float4*)(S_all + (lane << 2));
  const float inv = 1.0f / ((float)N_NODES + Z);
  float4 o;
  o.x = (sa.x + acc.x) * inv;
  o.y = (sa.y + acc.y) * inv;
  o.z = (sa.z + acc.z) * inv;
  o.w = (sa.w + acc.w) * inv;
  *(float4*)(out + (size_t)row * DIM + (lane << 2)) = o;
}

extern "C" void kernel_launch(void* const* d_in, const int* in_sizes, int n_in,
                              void* d_out, int out_size, void* d_ws, size_t ws_size,
                              hipStream_t stream) {
  const float* x = (const float*)d_in[0];
  const int* ei = (const int*)d_in[1];
  const float* W = (const float*)d_in[2];
  const float* a = (const float*)d_in[3];
  float* out = (float*)d_out;

  unsigned char* ws = (unsigned char*)d_ws;
  float* h = (float*)(ws + OFF_H);
  unsigned int* bitmap = (unsigned int*)(ws + OFF_BITMAP);
  int* cnt = (int*)(ws + OFF_CNT);
  int* cursor = (int*)(ws + OFF_CURSOR);
  float* S_all = (float*)(ws + OFF_SALL);
  float* sv = (float*)(ws + OFF_S);
  float* tv = (float*)(ws + OFF_T);
  int* rowstart = (int*)(ws + OFF_ROWSTART);
  unsigned char* flags = (unsigned char*)(ws + OFF_FLAGS);
  int* csr = (int*)(ws + OFF_CSR);

  // zero: bitmap + cnt + cursor + S_all (contiguous region)
  hipMemsetAsync(ws + ZERO_BASE, 0, ZERO_BYTES, stream);

  gemm_kernel<<<dim3(N_NODES / 64, DIM / 64), 256, 0, stream>>>(x, W, h);
  st_kernel<<<N_NODES / 4, 256, 0, stream>>>(h, a, sv, tv);
  colsum_kernel<<<64, 256, 0, stream>>>(h, S_all);
  flag_count_kernel<<<E_EDGES / 256, 256, 0, stream>>>(ei, bitmap, cnt, flags);
  scan_kernel<<<1, 256, 0, stream>>>(cnt, rowstart);
  scatter_kernel<<<E_EDGES / 256, 256, 0, stream>>>(ei, flags, rowstart, cursor, csr);
  row_kernel<<<N_NODES / 4, 256, 0, stream>>>(h, sv, tv, S_all, rowstart, csr, out);
}